// Round 17
// baseline (364.168 us; speedup 1.0000x reference)
//
#include <hip/hip_runtime.h>

// dims
#define L_   384
#define D_   512
#define C_   256
#define H_   4
#define RR_  256
#define M1_  98304   // R*L
#define LL2_ 147456  // L*L
#define NPAIR_BLOCKS 18480  // 73920 pairs / 4 waves per block
#define NLN_BLOCKS 24576    // M1/4

typedef __bf16 bf16x8 __attribute__((ext_vector_type(8)));
typedef float f32x4 __attribute__((ext_vector_type(4)));

__device__ __forceinline__ unsigned short f2bf_bits(float f) {
  union { float f; unsigned u; } v; v.f = f;
  return (unsigned short)((v.u + 0x7fffu + ((v.u >> 16) & 1u)) >> 16);
}
__device__ __forceinline__ __bf16 f2bf(float f) {
  union { unsigned short s; __bf16 b; } o; o.s = f2bf_bits(f);
  return o.b;
}

// ------- K1 fat: LayerNorm(x) -> msa ∥ W transposes (resource-compatible) ----
__global__ __launch_bounds__(256) void ln_wtrans_kernel(
    const float* __restrict__ x, const float* __restrict__ g,
    const float* __restrict__ b, __bf16* __restrict__ msa,
    const float* __restrict__ Wv, const float* __restrict__ Wo,
    __bf16* __restrict__ WvT, __bf16* __restrict__ WoT) {
  if (blockIdx.x < NLN_BLOCKS) {
    int row = blockIdx.x * 4 + (threadIdx.x >> 6);
    int lane = threadIdx.x & 63;
    const float4* xr = (const float4*)(x + (size_t)row * D_ + lane * 8);
    float4 v0 = xr[0], v1 = xr[1];
    float s1 = v0.x + v0.y + v0.z + v0.w + v1.x + v1.y + v1.z + v1.w;
    float s2 = v0.x * v0.x + v0.y * v0.y + v0.z * v0.z + v0.w * v0.w +
               v1.x * v1.x + v1.y * v1.y + v1.z * v1.z + v1.w * v1.w;
#pragma unroll
    for (int o = 32; o > 0; o >>= 1) {
      s1 += __shfl_xor(s1, o);
      s2 += __shfl_xor(s2, o);
    }
    float mu = s1 * (1.0f / D_);
    float var = s2 * (1.0f / D_) - mu * mu;
    float rs = rsqrtf(var + 1e-5f);
    const float4* gp = (const float4*)(g + lane * 8);
    const float4* bp = (const float4*)(b + lane * 8);
    float4 g0 = gp[0], g1 = gp[1], b0 = bp[0], b1 = bp[1];
    float y[8];
    y[0] = (v0.x - mu) * rs * g0.x + b0.x;
    y[1] = (v0.y - mu) * rs * g0.y + b0.y;
    y[2] = (v0.z - mu) * rs * g0.z + b0.z;
    y[3] = (v0.w - mu) * rs * g0.w + b0.w;
    y[4] = (v1.x - mu) * rs * g1.x + b1.x;
    y[5] = (v1.y - mu) * rs * g1.y + b1.y;
    y[6] = (v1.z - mu) * rs * g1.z + b1.z;
    y[7] = (v1.w - mu) * rs * g1.w + b1.w;
    uint4 pk;
    pk.x = ((unsigned)f2bf_bits(y[1]) << 16) | f2bf_bits(y[0]);
    pk.y = ((unsigned)f2bf_bits(y[3]) << 16) | f2bf_bits(y[2]);
    pk.z = ((unsigned)f2bf_bits(y[5]) << 16) | f2bf_bits(y[4]);
    pk.w = ((unsigned)f2bf_bits(y[7]) << 16) | f2bf_bits(y[6]);
    *(uint4*)(msa + (size_t)row * D_ + lane * 8) = pk;
  } else {
    int id = (blockIdx.x - NLN_BLOCKS) * 256 + threadIdx.x;  // 0..524287
    int m = id >> 18;
    int e = (id >> 9) & 511, d = id & 511;
    const float* W = m ? Wo : Wv;
    __bf16* T = m ? WoT : WvT;
    T[(size_t)e * 512 + d] = f2bf(W[(size_t)d * 512 + e]);
  }
}

// ------ K3: pair symmetrize + LN + per-head logits (+mask), standalone ------
__global__ __launch_bounds__(256) void pair_logits_kernel(
    const float* __restrict__ pf, const int* __restrict__ mask,
    const float* __restrict__ g, const float* __restrict__ b,
    const float* __restrict__ Wp, float* __restrict__ logits) {
  unsigned wid = blockIdx.x * 4 + (threadIdx.x >> 6);  // 0..73919
  int lane = threadIdx.x & 63;
  unsigned a = wid / 385u;
  unsigned c = wid - a * 385u;
  int i, j;
  if (c < 384u - a) { i = a; j = a + c; }
  else { i = 383 - a; j = i + (c - (384 - a)); }

  int c0 = lane * 4;
  float4 p1 = *(const float4*)(pf + ((size_t)i * L_ + j) * C_ + c0);
  float4 p2 = *(const float4*)(pf + ((size_t)j * L_ + i) * C_ + c0);
  float4 v;
  v.x = 0.5f * (p1.x + p2.x); v.y = 0.5f * (p1.y + p2.y);
  v.z = 0.5f * (p1.z + p2.z); v.w = 0.5f * (p1.w + p2.w);
  float s1 = v.x + v.y + v.z + v.w;
  float s2 = v.x * v.x + v.y * v.y + v.z * v.z + v.w * v.w;
#pragma unroll
  for (int o = 32; o > 0; o >>= 1) {
    s1 += __shfl_xor(s1, o);
    s2 += __shfl_xor(s2, o);
  }
  float mu = s1 * (1.0f / C_);
  float var = s2 * (1.0f / C_) - mu * mu;
  float rs = rsqrtf(var + 1e-5f);
  float4 gv = *(const float4*)(g + c0);
  float4 bv = *(const float4*)(b + c0);
  float y0 = (v.x - mu) * rs * gv.x + bv.x;
  float y1 = (v.y - mu) * rs * gv.y + bv.y;
  float y2 = (v.z - mu) * rs * gv.z + bv.z;
  float y3 = (v.w - mu) * rs * gv.w + bv.w;
  const float4* wp = (const float4*)Wp;  // [256][4]
  float4 w0 = wp[c0], w1 = wp[c0 + 1], w2 = wp[c0 + 2], w3 = wp[c0 + 3];
  float4 t;
  t.x = y0 * w0.x + y1 * w1.x + y2 * w2.x + y3 * w3.x;
  t.y = y0 * w0.y + y1 * w1.y + y2 * w2.y + y3 * w3.y;
  t.z = y0 * w0.z + y1 * w1.z + y2 * w2.z + y3 * w3.z;
  t.w = y0 * w0.w + y1 * w1.w + y2 * w2.w + y3 * w3.w;
#pragma unroll
  for (int o = 32; o > 0; o >>= 1) {
    t.x += __shfl_xor(t.x, o);
    t.y += __shfl_xor(t.y, o);
    t.z += __shfl_xor(t.z, o);
    t.w += __shfl_xor(t.w, o);
  }
  if (lane < 8) {
    int h = lane & 3;
    int ii = (lane < 4) ? i : j;
    int jj = (lane < 4) ? j : i;
    bool ok = (mask[i] != 0) && (mask[j] != 0);
    const float NEG = -3.402823466e38f;
    const float SCALE = (float)(0.08838834764831845 / 19.595917942265423);
    float th = (h == 0) ? t.x : (h == 1) ? t.y : (h == 2) ? t.z : t.w;
    logits[(size_t)h * LL2_ + (size_t)ii * L_ + jj] = ok ? SCALE * th : NEG;
  }
}

// ---------------- K4: row softmax -> attn (bf16) ----------------
__global__ __launch_bounds__(256) void softmax_kernel(
    const float* __restrict__ logits, __bf16* __restrict__ attn) {
  int wave = threadIdx.x >> 6, lane = threadIdx.x & 63;
  int row = blockIdx.x * 4 + wave;  // 0..1535 (= h*384 + i)
  const float* lr = logits + (size_t)row * L_;
  float v[6];
#pragma unroll
  for (int t = 0; t < 6; ++t) v[t] = lr[lane + t * 64];
  float mx = v[0];
#pragma unroll
  for (int t = 1; t < 6; ++t) mx = fmaxf(mx, v[t]);
#pragma unroll
  for (int o = 32; o > 0; o >>= 1) mx = fmaxf(mx, __shfl_xor(mx, o));
  float s = 0.f;
#pragma unroll
  for (int t = 0; t < 6; ++t) { v[t] = __expf(v[t] - mx); s += v[t]; }
#pragma unroll
  for (int o = 32; o > 0; o >>= 1) s += __shfl_xor(s, o);
  float inv = 1.0f / s;
  __bf16* ar = attn + (size_t)row * L_;
#pragma unroll
  for (int t = 0; t < 6; ++t) ar[lane + t * 64] = f2bf(v[t] * inv);
}

// ---------------- shared GEMM machinery (BK=32) ----------------
__device__ __forceinline__ void gload16(const void* g, void* l) {
  __builtin_amdgcn_global_load_lds(
      (const __attribute__((address_space(1))) void*)g,
      (__attribute__((address_space(3))) void*)l, 16, 0, 0);
}

__device__ __forceinline__ unsigned xcd_swz_768(unsigned bid) {
  return (bid & 7u) * 96u + (bid >> 3);
}
__device__ __forceinline__ unsigned xcd_swz_1024(unsigned bid) {
  return (bid & 7u) * 128u + (bid >> 3);
}

// LDS row of 64B = 4 chunks of 16B; conflict-free swizzle uses (row>>1)&3.
template <int NT>
__device__ __forceinline__ void stage_part32(__bf16* s, const __bf16* g, size_t ld) {
  int tid = threadIdx.x;
#pragma unroll
  for (int i = 0; i < 2; ++i) {
    int cid = i * NT + tid;
    int row = cid >> 2, c = cid & 3;
    int cs = c ^ ((row >> 1) & 3);
    gload16(g + (size_t)row * ld + cs * 8, (char*)s + cid * 16);
  }
}

__device__ __forceinline__ bf16x8 frag_ld32(const __bf16* s, int row, int fk) {
  int c = (fk >> 3) ^ ((row >> 1) & 3);
  return *(const bf16x8*)((const char*)s + row * 64 + c * 16);
}

// ---- 256x256 tile, 512 thr, 8 waves, BK=32, 2-slot ping-pong (64 KB) ----
__device__ __forceinline__ void mainloop256_2s(
    const __bf16* __restrict__ A, size_t ldA,
    const __bf16* __restrict__ B, size_t ldB,
    int K, __bf16* lds, f32x4 acc[8][4]) {
  int lane = threadIdx.x & 63, wave = threadIdx.x >> 6;
  int wm = (wave >> 2) * 128, wn = (wave & 3) * 64;
  int fr = lane & 15, fk = (lane >> 4) * 8;
  int nt = K >> 5;
  const int SLOT = 512 * 32;
  stage_part32<512>(lds, A, ldA);
  stage_part32<512>(lds + 256 * 32, B, ldB);
  for (int t = 0; t < nt; ++t) {
    const __bf16* As = lds + (t & 1) * SLOT;
    const __bf16* Bs = As + 256 * 32;
    if (t + 1 < nt) {
      __bf16* d = lds + ((t + 1) & 1) * SLOT;
      stage_part32<512>(d, A + (size_t)(t + 1) * 32, ldA);
      stage_part32<512>(d + 256 * 32, B + (size_t)(t + 1) * 32, ldB);
      asm volatile("s_waitcnt vmcnt(4)" ::: "memory");
    } else {
      asm volatile("s_waitcnt vmcnt(0)" ::: "memory");
    }
    __builtin_amdgcn_s_barrier();
    bf16x8 bfv[4];
#pragma unroll
    for (int ni = 0; ni < 4; ++ni) bfv[ni] = frag_ld32(Bs, wn + ni * 16 + fr, fk);
#pragma unroll
    for (int half = 0; half < 2; ++half) {
      bf16x8 af[4];
#pragma unroll
      for (int mi = 0; mi < 4; ++mi)
        af[mi] = frag_ld32(As, wm + half * 64 + mi * 16 + fr, fk);
      __builtin_amdgcn_s_setprio(1);
#pragma unroll
      for (int mi = 0; mi < 4; ++mi)
#pragma unroll
        for (int ni = 0; ni < 4; ++ni)
          acc[half * 4 + mi][ni] = __builtin_amdgcn_mfma_f32_16x16x32_bf16(
              af[mi], bfv[ni], acc[half * 4 + mi][ni], 0, 0, 0);
      __builtin_amdgcn_s_setprio(0);
    }
  }
}

// ---- K2: VT[e][m] = sum_d WvT[e][d] * msa[m][d], 256^2 / 2-slot ----
__global__ __launch_bounds__(512) void gemm_vt_kernel(
    const __bf16* __restrict__ WvT, const __bf16* __restrict__ msa,
    __bf16* __restrict__ VT) {
  __shared__ __bf16 lds[2 * 512 * 32];  // 64 KB (reused by epilogue repack)
  unsigned swz = xcd_swz_768(blockIdx.x + 2 * blockIdx.y);
  int m0 = (swz & 1) * 256;        // e-tile
  int n0 = (swz >> 1) * 256;       // msa panel
  f32x4 acc[8][4] = {};
  mainloop256_2s(WvT + (size_t)m0 * D_, D_, msa + (size_t)n0 * D_, D_, D_, lds, acc);
  int lane = threadIdx.x & 63, wave = threadIdx.x >> 6;
  int wn = (wave & 3) * 64;
  int cr = (lane >> 4) * 4, cc = lane & 15;
  __bf16* Ep = lds;  // [64][256] bf16 per pass

  __syncthreads();
#pragma unroll
  for (int p = 0; p < 4; ++p) {
    if ((wave >> 2) == (p >> 1)) {
      int mi0 = (p & 1) * 4;
#pragma unroll
      for (int mi = 0; mi < 4; ++mi)
#pragma unroll
        for (int ni = 0; ni < 4; ++ni)
#pragma unroll
          for (int rr = 0; rr < 4; ++rr) {
            int rowl = mi * 16 + cr + rr;        // 0..63
            int col = wn + ni * 16 + cc;         // 0..255
            int cch = col >> 3;
            Ep[rowl * 256 + (((cch ^ (rowl & 31)) << 3) | (col & 7))] =
                f2bf(acc[mi0 + mi][ni][rr]);
          }
    }
    __syncthreads();
#pragma unroll
    for (int s = 0; s < 4; ++s) {
      int rowl = wave * 8 + s * 2 + (lane >> 5);
      int cch = lane & 31;
      bf16x8 v = *(const bf16x8*)&Ep[rowl * 256 + ((cch ^ (rowl & 31)) << 3)];
      int e = m0 + p * 64 + rowl;
      *(bf16x8*)(VT + (size_t)e * M1_ + n0 + cch * 8) = v;
    }
    __syncthreads();
  }
}

// ---- K5 v2: one block per (h,r); M-tile = 384 (full i-range), N = 128 ----
// out2[(r,i)][h*128+e] = sum_j attn_h[i][j] * VT[h*128+e][r*384+j]
// VT slab staged ONCE per (h,r) (was 3x); 8 waves (4M x 2N), per-wave 96x64.
__global__ __launch_bounds__(512) void attnv_kernel(
    const __bf16* __restrict__ attn, const __bf16* __restrict__ VT,
    __bf16* __restrict__ out2) {
  __shared__ __bf16 lds[2 * (384 + 128) * 32];  // 64 KB: 2 slots (A 24KB + B 8KB)
  unsigned swz = xcd_swz_1024(blockIdx.x);  // 1024 blocks; h fixed per XCD chunk
  int h = swz >> 8, r = swz & 255;
  const __bf16* A = attn + (size_t)h * LL2_;                 // 384 x 384, ld L_
  const __bf16* B = VT + (size_t)(h * 128) * M1_ + (size_t)r * L_;  // 128 rows, ld M1_
  int tid = threadIdx.x, lane = tid & 63, wave = tid >> 6;
  int fr = lane & 15, fk = (lane >> 4) * 8;
  int wm = (wave >> 1) * 96, wn = (wave & 1) * 64;
  const int SLOT = (384 + 128) * 32;

  auto stage = [&](__bf16* slot, int t) {
    // A part: 384 rows x 4 chunks = 1536 -> 3 loads/thread
#pragma unroll
    for (int i = 0; i < 3; ++i) {
      int cid = i * 512 + tid;
      int row = cid >> 2, c = cid & 3;
      int cs = c ^ ((row >> 1) & 3);
      gload16(A + (size_t)row * L_ + t * 32 + cs * 8, (char*)slot + cid * 16);
    }
    // B part: 128 rows x 4 chunks = 512 -> 1 load/thread
    {
      int row = tid >> 2, c = tid & 3;
      int cs = c ^ ((row >> 1) & 3);
      gload16(B + (size_t)row * M1_ + t * 32 + cs * 8,
              (char*)(slot + 384 * 32) + tid * 16);
    }
  };

  f32x4 acc[6][4] = {};  // 96 x 64 per wave
  stage(lds, 0);
  const int NT = 12;
  for (int t = 0; t < NT; ++t) {
    const __bf16* As = lds + (t & 1) * SLOT;
    const __bf16* Bs = As + 384 * 32;
    if (t + 1 < NT) {
      stage(lds + ((t + 1) & 1) * SLOT, t + 1);
      asm volatile("s_waitcnt vmcnt(4)" ::: "memory");
    } else {
      asm volatile("s_waitcnt vmcnt(0)" ::: "memory");
    }
    __builtin_amdgcn_s_barrier();
    bf16x8 bfv[4];
#pragma unroll
    for (int ni = 0; ni < 4; ++ni) bfv[ni] = frag_ld32(Bs, wn + ni * 16 + fr, fk);
#pragma unroll
    for (int half = 0; half < 2; ++half) {
      bf16x8 af[3];
#pragma unroll
      for (int mi = 0; mi < 3; ++mi)
        af[mi] = frag_ld32(As, wm + half * 48 + mi * 16 + fr, fk);
      __builtin_amdgcn_s_setprio(1);
#pragma unroll
      for (int mi = 0; mi < 3; ++mi)
#pragma unroll
        for (int ni = 0; ni < 4; ++ni)
          acc[half * 3 + mi][ni] = __builtin_amdgcn_mfma_f32_16x16x32_bf16(
              af[mi], bfv[ni], acc[half * 3 + mi][ni], 0, 0, 0);
      __builtin_amdgcn_s_setprio(0);
    }
  }

  // epilogue: 3 passes of [128 i][128 e] bf16 repack -> bf16x8 stores
  int cr = (lane >> 4) * 4, cc = lane & 15;
  __bf16* Ep = lds;
  __syncthreads();
#pragma unroll
  for (int p = 0; p < 3; ++p) {
#pragma unroll
    for (int mi = 0; mi < 6; ++mi) {
      int gr = wm + mi * 16;  // fragment row block base (0..368)
      if ((gr >> 7) == p) {
#pragma unroll
        for (int ni = 0; ni < 4; ++ni)
#pragma unroll
          for (int rr = 0; rr < 4; ++rr) {
            int il = (gr & 127) + cr + rr;       // 0..127 within pass
            int el = wn + ni * 16 + cc;          // 0..127
            int cch = el >> 3;
            Ep[il * 128 + (((cch ^ (il & 15)) << 3) | (el & 7))] =
                f2bf(acc[mi][ni][rr]);
          }
      }
    }
    __syncthreads();
#pragma unroll
    for (int s = 0; s < 4; ++s) {
      int chunkid = s * 512 + tid;   // 0..2047
      int il = chunkid >> 4, cch = chunkid & 15;
      bf16x8 v = *(const bf16x8*)&Ep[il * 128 + ((cch ^ (il & 15)) << 3)];
      int grow = r * L_ + p * 128 + il;
      *(bf16x8*)(out2 + (size_t)grow * D_ + h * 128 + cch * 8) = v;
    }
    __syncthreads();
  }
}

// ---- K6: out[m][f] = x[m][f] + sum_e out2[m][e] * WoT[f][e], 256^2 / 2-slot ----
__global__ __launch_bounds__(512) void gemm_out_kernel(
    const __bf16* __restrict__ out2, const __bf16* __restrict__ WoT,
    const float* __restrict__ x, float* __restrict__ out) {
  __shared__ __bf16 lds[2 * 512 * 32];  // 64 KB (reused by epilogue repack)
  unsigned swz = xcd_swz_768(blockIdx.x + 2 * blockIdx.y);
  int n0 = (swz & 1) * 256;
  int m0 = (swz >> 1) * 256;
  f32x4 acc[8][4] = {};
  mainloop256_2s(out2 + (size_t)m0 * D_, D_, WoT + (size_t)n0 * D_, D_, D_, lds, acc);
  int lane = threadIdx.x & 63, wave = threadIdx.x >> 6;
  int wn = (wave & 3) * 64;
  int cr = (lane >> 4) * 4, cc = lane & 15;
  float* Ep = (float*)lds;  // [64][256] f32 per pass, chunk-XOR swizzled

  __syncthreads();  // all waves done with mainloop LDS
#pragma unroll
  for (int p = 0; p < 4; ++p) {
    if ((wave >> 2) == (p >> 1)) {
      int mi0 = (p & 1) * 4;
#pragma unroll
      for (int mi = 0; mi < 4; ++mi)
#pragma unroll
        for (int ni = 0; ni < 4; ++ni)
#pragma unroll
          for (int rr = 0; rr < 4; ++rr) {
            int rowl = mi * 16 + cr + rr;            // 0..63
            int col = wn + ni * 16 + cc;             // 0..255
            int c4 = col >> 2;
            Ep[rowl * 256 + (((c4 ^ (rowl & 15)) << 2) | (col & 3))] =
                acc[mi0 + mi][ni][rr];
          }
    }
    __syncthreads();
#pragma unroll
    for (int s = 0; s < 8; ++s) {
      int rowl = wave * 8 + s;
      int grow = m0 + p * 64 + rowl;
      float4 v = *(float4*)&Ep[rowl * 256 + ((lane ^ (rowl & 15)) << 2)];
      float4 xv = *(const float4*)(x + (size_t)grow * D_ + n0 + lane * 4);
      v.x += xv.x; v.y += xv.y; v.z += xv.z; v.w += xv.w;
      *(float4*)(out + (size_t)grow * D_ + n0 + lane * 4) = v;
    }
    __syncthreads();
  }
}

extern "C" void kernel_launch(void* const* d_in, const int* in_sizes, int n_in,
                              void* d_out, int out_size, void* d_ws, size_t ws_size,
                              hipStream_t stream) {
  const float* x      = (const float*)d_in[0];
  const float* pair   = (const float*)d_in[1];
  const int*   mask   = (const int*)d_in[2];
  const float* g_msa  = (const float*)d_in[3];
  const float* b_msa  = (const float*)d_in[4];
  const float* g_pair = (const float*)d_in[5];
  const float* b_pair = (const float*)d_in[6];
  const float* Wp     = (const float*)d_in[7];
  const float* Wv     = (const float*)d_in[8];
  const float* Wo     = (const float*)d_in[9];
  float* out = (float*)d_out;

  char* p = (char*)d_ws;
  auto alloc = [&](size_t bytes) {
    char* r = p;
    p += (bytes + 255) & ~(size_t)255;
    return r;
  };
  __bf16* msa    = (__bf16*)alloc((size_t)M1_ * D_ * 2);  // 100.7 MB (reused as out2)
  __bf16* VT     = (__bf16*)alloc((size_t)D_ * M1_ * 2);  // 100.7 MB
  float*  logits = (float*)alloc((size_t)H_ * LL2_ * 4);  // 2.36 MB
  __bf16* attn   = (__bf16*)alloc((size_t)H_ * LL2_ * 2); // 1.18 MB
  __bf16* WvT    = (__bf16*)alloc((size_t)512 * 512 * 2);
  __bf16* WoT    = (__bf16*)alloc((size_t)512 * 512 * 2);
  __bf16* out2   = msa;  // msa dead after gemm_vt_kernel

  ln_wtrans_kernel<<<NLN_BLOCKS + 2048, 256, 0, stream>>>(
      x, g_msa, b_msa, msa, Wv, Wo, WvT, WoT);
  gemm_vt_kernel<<<dim3(2, M1_ / 256), 512, 0, stream>>>(WvT, msa, VT);
  pair_logits_kernel<<<NPAIR_BLOCKS, 256, 0, stream>>>(pair, mask, g_pair, b_pair, Wp, logits);
  softmax_kernel<<<(H_ * L_) / 4, 256, 0, stream>>>(logits, attn);
  attnv_kernel<<<H_ * RR_, 512, 0, stream>>>(attn, VT, out2);
  gemm_out_kernel<<<dim3(2, M1_ / 256), 512, 0, stream>>>(out2, WoT, x, out);
}

// Round 18
// 357.478 us; speedup vs baseline: 1.0187x; 1.0187x over previous
//
#include <hip/hip_runtime.h>

// dims
#define L_   384
#define D_   512
#define C_   256
#define H_   4
#define RR_  256
#define M1_  98304   // R*L
#define LL2_ 147456  // L*L
#define NPAIR_BLOCKS 18480  // 73920 pairs / 4 waves per block
#define NLN_BLOCKS 24576    // M1/4

typedef __bf16 bf16x8 __attribute__((ext_vector_type(8)));
typedef float f32x4 __attribute__((ext_vector_type(4)));

__device__ __forceinline__ unsigned short f2bf_bits(float f) {
  union { float f; unsigned u; } v; v.f = f;
  return (unsigned short)((v.u + 0x7fffu + ((v.u >> 16) & 1u)) >> 16);
}
__device__ __forceinline__ __bf16 f2bf(float f) {
  union { unsigned short s; __bf16 b; } o; o.s = f2bf_bits(f);
  return o.b;
}

// ------- K1 fat: LayerNorm(x) -> msa ∥ W transposes (resource-compatible) ----
__global__ __launch_bounds__(256) void ln_wtrans_kernel(
    const float* __restrict__ x, const float* __restrict__ g,
    const float* __restrict__ b, __bf16* __restrict__ msa,
    const float* __restrict__ Wv, const float* __restrict__ Wo,
    __bf16* __restrict__ WvT, __bf16* __restrict__ WoT) {
  if (blockIdx.x < NLN_BLOCKS) {
    int row = blockIdx.x * 4 + (threadIdx.x >> 6);
    int lane = threadIdx.x & 63;
    const float4* xr = (const float4*)(x + (size_t)row * D_ + lane * 8);
    float4 v0 = xr[0], v1 = xr[1];
    float s1 = v0.x + v0.y + v0.z + v0.w + v1.x + v1.y + v1.z + v1.w;
    float s2 = v0.x * v0.x + v0.y * v0.y + v0.z * v0.z + v0.w * v0.w +
               v1.x * v1.x + v1.y * v1.y + v1.z * v1.z + v1.w * v1.w;
#pragma unroll
    for (int o = 32; o > 0; o >>= 1) {
      s1 += __shfl_xor(s1, o);
      s2 += __shfl_xor(s2, o);
    }
    float mu = s1 * (1.0f / D_);
    float var = s2 * (1.0f / D_) - mu * mu;
    float rs = rsqrtf(var + 1e-5f);
    const float4* gp = (const float4*)(g + lane * 8);
    const float4* bp = (const float4*)(b + lane * 8);
    float4 g0 = gp[0], g1 = gp[1], b0 = bp[0], b1 = bp[1];
    float y[8];
    y[0] = (v0.x - mu) * rs * g0.x + b0.x;
    y[1] = (v0.y - mu) * rs * g0.y + b0.y;
    y[2] = (v0.z - mu) * rs * g0.z + b0.z;
    y[3] = (v0.w - mu) * rs * g0.w + b0.w;
    y[4] = (v1.x - mu) * rs * g1.x + b1.x;
    y[5] = (v1.y - mu) * rs * g1.y + b1.y;
    y[6] = (v1.z - mu) * rs * g1.z + b1.z;
    y[7] = (v1.w - mu) * rs * g1.w + b1.w;
    uint4 pk;
    pk.x = ((unsigned)f2bf_bits(y[1]) << 16) | f2bf_bits(y[0]);
    pk.y = ((unsigned)f2bf_bits(y[3]) << 16) | f2bf_bits(y[2]);
    pk.z = ((unsigned)f2bf_bits(y[5]) << 16) | f2bf_bits(y[4]);
    pk.w = ((unsigned)f2bf_bits(y[7]) << 16) | f2bf_bits(y[6]);
    *(uint4*)(msa + (size_t)row * D_ + lane * 8) = pk;
  } else {
    int id = (blockIdx.x - NLN_BLOCKS) * 256 + threadIdx.x;  // 0..524287
    int m = id >> 18;
    int e = (id >> 9) & 511, d = id & 511;
    const float* W = m ? Wo : Wv;
    __bf16* T = m ? WoT : WvT;
    T[(size_t)e * 512 + d] = f2bf(W[(size_t)d * 512 + e]);
  }
}

// ------ K3: pair symmetrize + LN + per-head logits (+mask), standalone ------
__global__ __launch_bounds__(256) void pair_logits_kernel(
    const float* __restrict__ pf, const int* __restrict__ mask,
    const float* __restrict__ g, const float* __restrict__ b,
    const float* __restrict__ Wp, float* __restrict__ logits) {
  unsigned wid = blockIdx.x * 4 + (threadIdx.x >> 6);  // 0..73919
  int lane = threadIdx.x & 63;
  unsigned a = wid / 385u;
  unsigned c = wid - a * 385u;
  int i, j;
  if (c < 384u - a) { i = a; j = a + c; }
  else { i = 383 - a; j = i + (c - (384 - a)); }

  int c0 = lane * 4;
  float4 p1 = *(const float4*)(pf + ((size_t)i * L_ + j) * C_ + c0);
  float4 p2 = *(const float4*)(pf + ((size_t)j * L_ + i) * C_ + c0);
  float4 v;
  v.x = 0.5f * (p1.x + p2.x); v.y = 0.5f * (p1.y + p2.y);
  v.z = 0.5f * (p1.z + p2.z); v.w = 0.5f * (p1.w + p2.w);
  float s1 = v.x + v.y + v.z + v.w;
  float s2 = v.x * v.x + v.y * v.y + v.z * v.z + v.w * v.w;
#pragma unroll
  for (int o = 32; o > 0; o >>= 1) {
    s1 += __shfl_xor(s1, o);
    s2 += __shfl_xor(s2, o);
  }
  float mu = s1 * (1.0f / C_);
  float var = s2 * (1.0f / C_) - mu * mu;
  float rs = rsqrtf(var + 1e-5f);
  float4 gv = *(const float4*)(g + c0);
  float4 bv = *(const float4*)(b + c0);
  float y0 = (v.x - mu) * rs * gv.x + bv.x;
  float y1 = (v.y - mu) * rs * gv.y + bv.y;
  float y2 = (v.z - mu) * rs * gv.z + bv.z;
  float y3 = (v.w - mu) * rs * gv.w + bv.w;
  const float4* wp = (const float4*)Wp;  // [256][4]
  float4 w0 = wp[c0], w1 = wp[c0 + 1], w2 = wp[c0 + 2], w3 = wp[c0 + 3];
  float4 t;
  t.x = y0 * w0.x + y1 * w1.x + y2 * w2.x + y3 * w3.x;
  t.y = y0 * w0.y + y1 * w1.y + y2 * w2.y + y3 * w3.y;
  t.z = y0 * w0.z + y1 * w1.z + y2 * w2.z + y3 * w3.z;
  t.w = y0 * w0.w + y1 * w1.w + y2 * w2.w + y3 * w3.w;
#pragma unroll
  for (int o = 32; o > 0; o >>= 1) {
    t.x += __shfl_xor(t.x, o);
    t.y += __shfl_xor(t.y, o);
    t.z += __shfl_xor(t.z, o);
    t.w += __shfl_xor(t.w, o);
  }
  if (lane < 8) {
    int h = lane & 3;
    int ii = (lane < 4) ? i : j;
    int jj = (lane < 4) ? j : i;
    bool ok = (mask[i] != 0) && (mask[j] != 0);
    const float NEG = -3.402823466e38f;
    const float SCALE = (float)(0.08838834764831845 / 19.595917942265423);
    float th = (h == 0) ? t.x : (h == 1) ? t.y : (h == 2) ? t.z : t.w;
    logits[(size_t)h * LL2_ + (size_t)ii * L_ + jj] = ok ? SCALE * th : NEG;
  }
}

// ---------------- K4: row softmax -> attn (bf16) ----------------
__global__ __launch_bounds__(256) void softmax_kernel(
    const float* __restrict__ logits, __bf16* __restrict__ attn) {
  int wave = threadIdx.x >> 6, lane = threadIdx.x & 63;
  int row = blockIdx.x * 4 + wave;  // 0..1535 (= h*384 + i)
  const float* lr = logits + (size_t)row * L_;
  float v[6];
#pragma unroll
  for (int t = 0; t < 6; ++t) v[t] = lr[lane + t * 64];
  float mx = v[0];
#pragma unroll
  for (int t = 1; t < 6; ++t) mx = fmaxf(mx, v[t]);
#pragma unroll
  for (int o = 32; o > 0; o >>= 1) mx = fmaxf(mx, __shfl_xor(mx, o));
  float s = 0.f;
#pragma unroll
  for (int t = 0; t < 6; ++t) { v[t] = __expf(v[t] - mx); s += v[t]; }
#pragma unroll
  for (int o = 32; o > 0; o >>= 1) s += __shfl_xor(s, o);
  float inv = 1.0f / s;
  __bf16* ar = attn + (size_t)row * L_;
#pragma unroll
  for (int t = 0; t < 6; ++t) ar[lane + t * 64] = f2bf(v[t] * inv);
}

// ---------------- shared GEMM machinery (BK=32) ----------------
__device__ __forceinline__ void gload16(const void* g, void* l) {
  __builtin_amdgcn_global_load_lds(
      (const __attribute__((address_space(1))) void*)g,
      (__attribute__((address_space(3))) void*)l, 16, 0, 0);
}

__device__ __forceinline__ unsigned xcd_swz_3072(unsigned bid) {
  return (bid & 7u) * 384u + (bid >> 3);
}
__device__ __forceinline__ unsigned xcd_swz_768(unsigned bid) {
  return (bid & 7u) * 96u + (bid >> 3);
}

// LDS row of 64B = 4 chunks of 16B; conflict-free swizzle uses (row>>1)&3.
template <int NT>
__device__ __forceinline__ void stage_part32(__bf16* s, const __bf16* g, size_t ld) {
  int tid = threadIdx.x;
#pragma unroll
  for (int i = 0; i < 2; ++i) {
    int cid = i * NT + tid;
    int row = cid >> 2, c = cid & 3;
    int cs = c ^ ((row >> 1) & 3);
    gload16(g + (size_t)row * ld + cs * 8, (char*)s + cid * 16);
  }
}

__device__ __forceinline__ bf16x8 frag_ld32(const __bf16* s, int row, int fk) {
  int c = (fk >> 3) ^ ((row >> 1) & 3);
  return *(const bf16x8*)((const char*)s + row * 64 + c * 16);
}

// ---- 256x256 tile, 512 thr, 8 waves, BK=32, 2-slot ping-pong (64 KB) ----
__device__ __forceinline__ void mainloop256_2s(
    const __bf16* __restrict__ A, size_t ldA,
    const __bf16* __restrict__ B, size_t ldB,
    int K, __bf16* lds, f32x4 acc[8][4]) {
  int lane = threadIdx.x & 63, wave = threadIdx.x >> 6;
  int wm = (wave >> 2) * 128, wn = (wave & 3) * 64;
  int fr = lane & 15, fk = (lane >> 4) * 8;
  int nt = K >> 5;
  const int SLOT = 512 * 32;
  stage_part32<512>(lds, A, ldA);
  stage_part32<512>(lds + 256 * 32, B, ldB);
  for (int t = 0; t < nt; ++t) {
    const __bf16* As = lds + (t & 1) * SLOT;
    const __bf16* Bs = As + 256 * 32;
    if (t + 1 < nt) {
      __bf16* d = lds + ((t + 1) & 1) * SLOT;
      stage_part32<512>(d, A + (size_t)(t + 1) * 32, ldA);
      stage_part32<512>(d + 256 * 32, B + (size_t)(t + 1) * 32, ldB);
      asm volatile("s_waitcnt vmcnt(4)" ::: "memory");
    } else {
      asm volatile("s_waitcnt vmcnt(0)" ::: "memory");
    }
    __builtin_amdgcn_s_barrier();
    bf16x8 bfv[4];
#pragma unroll
    for (int ni = 0; ni < 4; ++ni) bfv[ni] = frag_ld32(Bs, wn + ni * 16 + fr, fk);
#pragma unroll
    for (int half = 0; half < 2; ++half) {
      bf16x8 af[4];
#pragma unroll
      for (int mi = 0; mi < 4; ++mi)
        af[mi] = frag_ld32(As, wm + half * 64 + mi * 16 + fr, fk);
      __builtin_amdgcn_s_setprio(1);
#pragma unroll
      for (int mi = 0; mi < 4; ++mi)
#pragma unroll
        for (int ni = 0; ni < 4; ++ni)
          acc[half * 4 + mi][ni] = __builtin_amdgcn_mfma_f32_16x16x32_bf16(
              af[mi], bfv[ni], acc[half * 4 + mi][ni], 0, 0, 0);
      __builtin_amdgcn_s_setprio(0);
    }
  }
}

// ---- 128x128 tile, 256 thr, 4 waves, BK=32, 4-slot ring (64 KB) ----
__device__ __forceinline__ void mainloop128(
    const __bf16* __restrict__ A, size_t ldA,
    const __bf16* __restrict__ B, size_t ldB,
    int K, __bf16* lds, f32x4 acc[4][4]) {
  int lane = threadIdx.x & 63, wave = threadIdx.x >> 6;
  int wm = (wave >> 1) * 64, wn = (wave & 1) * 64;
  int fr = lane & 15, fk = (lane >> 4) * 8;
  int nt = K >> 5;
  const int SLOT = 256 * 32;
#pragma unroll
  for (int t = 0; t < 3; ++t) {
    stage_part32<256>(lds + t * SLOT, A + t * 32, ldA);
    stage_part32<256>(lds + t * SLOT + 128 * 32, B + t * 32, ldB);
  }
  for (int t = 0; t < nt; ++t) {
    int rem = nt - 1 - t;
    if (rem >= 2)      asm volatile("s_waitcnt vmcnt(8)" ::: "memory");
    else if (rem == 1) asm volatile("s_waitcnt vmcnt(4)" ::: "memory");
    else               asm volatile("s_waitcnt vmcnt(0)" ::: "memory");
    __builtin_amdgcn_s_barrier();
    const __bf16* As = lds + (t & 3) * SLOT;
    const __bf16* Bs = As + 128 * 32;
    if (t + 3 < nt) {
      __bf16* d = lds + ((t + 3) & 3) * SLOT;
      stage_part32<256>(d, A + (size_t)(t + 3) * 32, ldA);
      stage_part32<256>(d + 128 * 32, B + (size_t)(t + 3) * 32, ldB);
    }
    bf16x8 bfv[4];
#pragma unroll
    for (int ni = 0; ni < 4; ++ni) bfv[ni] = frag_ld32(Bs, wn + ni * 16 + fr, fk);
#pragma unroll
    for (int half = 0; half < 2; ++half) {
      bf16x8 af[2];
#pragma unroll
      for (int mi = 0; mi < 2; ++mi)
        af[mi] = frag_ld32(As, wm + half * 32 + mi * 16 + fr, fk);
      __builtin_amdgcn_s_setprio(1);
#pragma unroll
      for (int mi = 0; mi < 2; ++mi)
#pragma unroll
        for (int ni = 0; ni < 4; ++ni)
          acc[half * 2 + mi][ni] = __builtin_amdgcn_mfma_f32_16x16x32_bf16(
              af[mi], bfv[ni], acc[half * 2 + mi][ni], 0, 0, 0);
      __builtin_amdgcn_s_setprio(0);
    }
  }
}

// ---- K2: VT[e][m] = sum_d WvT[e][d] * msa[m][d], 256^2 / 2-slot ----
__global__ __launch_bounds__(512) void gemm_vt_kernel(
    const __bf16* __restrict__ WvT, const __bf16* __restrict__ msa,
    __bf16* __restrict__ VT) {
  __shared__ __bf16 lds[2 * 512 * 32];  // 64 KB (reused by epilogue repack)
  unsigned swz = xcd_swz_768(blockIdx.x + 2 * blockIdx.y);
  int m0 = (swz & 1) * 256;        // e-tile
  int n0 = (swz >> 1) * 256;       // msa panel
  f32x4 acc[8][4] = {};
  mainloop256_2s(WvT + (size_t)m0 * D_, D_, msa + (size_t)n0 * D_, D_, D_, lds, acc);
  int lane = threadIdx.x & 63, wave = threadIdx.x >> 6;
  int wn = (wave & 3) * 64;
  int cr = (lane >> 4) * 4, cc = lane & 15;
  __bf16* Ep = lds;  // [64][256] bf16 per pass

  __syncthreads();
#pragma unroll
  for (int p = 0; p < 4; ++p) {
    if ((wave >> 2) == (p >> 1)) {
      int mi0 = (p & 1) * 4;
#pragma unroll
      for (int mi = 0; mi < 4; ++mi)
#pragma unroll
        for (int ni = 0; ni < 4; ++ni)
#pragma unroll
          for (int rr = 0; rr < 4; ++rr) {
            int rowl = mi * 16 + cr + rr;        // 0..63
            int col = wn + ni * 16 + cc;         // 0..255
            int cch = col >> 3;
            Ep[rowl * 256 + (((cch ^ (rowl & 31)) << 3) | (col & 7))] =
                f2bf(acc[mi0 + mi][ni][rr]);
          }
    }
    __syncthreads();
#pragma unroll
    for (int s = 0; s < 4; ++s) {
      int rowl = wave * 8 + s * 2 + (lane >> 5);
      int cch = lane & 31;
      bf16x8 v = *(const bf16x8*)&Ep[rowl * 256 + ((cch ^ (rowl & 31)) << 3)];
      int e = m0 + p * 64 + rowl;
      *(bf16x8*)(VT + (size_t)e * M1_ + n0 + cch * 8) = v;
    }
    __syncthreads();
  }
}

// ---- K5: out2[(r,i)][h*128+d] = sum_j attn[h][i][j] * VT[h*128+d][r*384+j] ----
__global__ __launch_bounds__(256) void attnv_kernel(
    const __bf16* __restrict__ attn, const __bf16* __restrict__ VT,
    __bf16* __restrict__ out2) {
  __shared__ __bf16 lds[4 * 256 * 32];  // 64 KB (reused by epilogue repack)
  unsigned swz = xcd_swz_3072(blockIdx.x + 3 * blockIdx.y);
  int it = swz % 3u;
  int rh = swz / 3u;
  int h = rh & 3, r = rh >> 2;
  const __bf16* A = attn + (size_t)h * LL2_ + (size_t)it * 128 * L_;
  const __bf16* Bt = VT + (size_t)(h * 128) * M1_ + (size_t)r * L_;
  f32x4 acc[4][4] = {};
  mainloop128(A, L_, Bt, M1_, L_, lds, acc);
  int lane = threadIdx.x & 63, wave = threadIdx.x >> 6;
  int wm = (wave >> 1) * 64, wn = (wave & 1) * 64;
  int cr = (lane >> 4) * 4, cc = lane & 15;
  __bf16* Ep = lds;  // [128][128] bf16

  __syncthreads();
#pragma unroll
  for (int mi = 0; mi < 4; ++mi)
#pragma unroll
    for (int ni = 0; ni < 4; ++ni)
#pragma unroll
      for (int rr = 0; rr < 4; ++rr) {
        int il = wm + mi * 16 + cr + rr;         // 0..127
        int el = wn + ni * 16 + cc;              // 0..127
        int cch = el >> 3;
        Ep[il * 128 + (((cch ^ (il & 15)) << 3) | (el & 7))] =
            f2bf(acc[mi][ni][rr]);
      }
  __syncthreads();
#pragma unroll
  for (int s = 0; s < 8; ++s) {
    int il = wave * 32 + s * 4 + (lane >> 4);
    int cch = lane & 15;
    bf16x8 v = *(const bf16x8*)&Ep[il * 128 + ((cch ^ (il & 15)) << 3)];
    *(bf16x8*)(out2 + ((size_t)(r * L_ + it * 128 + il)) * D_ + h * 128 + cch * 8) = v;
  }
}

// ---- K6: out[m][f] = x[m][f] + sum_e out2[m][e] * WoT[f][e], 256^2 / 2-slot ----
__global__ __launch_bounds__(512) void gemm_out_kernel(
    const __bf16* __restrict__ out2, const __bf16* __restrict__ WoT,
    const float* __restrict__ x, float* __restrict__ out) {
  __shared__ __bf16 lds[2 * 512 * 32];  // 64 KB (reused by epilogue repack)
  unsigned swz = xcd_swz_768(blockIdx.x + 2 * blockIdx.y);
  int n0 = (swz & 1) * 256;
  int m0 = (swz >> 1) * 256;
  f32x4 acc[8][4] = {};
  mainloop256_2s(out2 + (size_t)m0 * D_, D_, WoT + (size_t)n0 * D_, D_, D_, lds, acc);
  int lane = threadIdx.x & 63, wave = threadIdx.x >> 6;
  int wn = (wave & 3) * 64;
  int cr = (lane >> 4) * 4, cc = lane & 15;
  float* Ep = (float*)lds;  // [64][256] f32 per pass, chunk-XOR swizzled

  __syncthreads();  // all waves done with mainloop LDS
#pragma unroll
  for (int p = 0; p < 4; ++p) {
    if ((wave >> 2) == (p >> 1)) {
      int mi0 = (p & 1) * 4;
#pragma unroll
      for (int mi = 0; mi < 4; ++mi)
#pragma unroll
        for (int ni = 0; ni < 4; ++ni)
#pragma unroll
          for (int rr = 0; rr < 4; ++rr) {
            int rowl = mi * 16 + cr + rr;            // 0..63
            int col = wn + ni * 16 + cc;             // 0..255
            int c4 = col >> 2;
            Ep[rowl * 256 + (((c4 ^ (rowl & 15)) << 2) | (col & 3))] =
                acc[mi0 + mi][ni][rr];
          }
    }
    __syncthreads();
#pragma unroll
    for (int s = 0; s < 8; ++s) {
      int rowl = wave * 8 + s;
      int grow = m0 + p * 64 + rowl;
      float4 v = *(float4*)&Ep[rowl * 256 + ((lane ^ (rowl & 15)) << 2)];
      float4 xv = *(const float4*)(x + (size_t)grow * D_ + n0 + lane * 4);
      v.x += xv.x; v.y += xv.y; v.z += xv.z; v.w += xv.w;
      *(float4*)(out + (size_t)grow * D_ + n0 + lane * 4) = v;
    }
    __syncthreads();
  }
}

extern "C" void kernel_launch(void* const* d_in, const int* in_sizes, int n_in,
                              void* d_out, int out_size, void* d_ws, size_t ws_size,
                              hipStream_t stream) {
  const float* x      = (const float*)d_in[0];
  const float* pair   = (const float*)d_in[1];
  const int*   mask   = (const int*)d_in[2];
  const float* g_msa  = (const float*)d_in[3];
  const float* b_msa  = (const float*)d_in[4];
  const float* g_pair = (const float*)d_in[5];
  const float* b_pair = (const float*)d_in[6];
  const float* Wp     = (const float*)d_in[7];
  const float* Wv     = (const float*)d_in[8];
  const float* Wo     = (const float*)d_in[9];
  float* out = (float*)d_out;

  char* p = (char*)d_ws;
  auto alloc = [&](size_t bytes) {
    char* r = p;
    p += (bytes + 255) & ~(size_t)255;
    return r;
  };
  __bf16* msa    = (__bf16*)alloc((size_t)M1_ * D_ * 2);  // 100.7 MB (reused as out2)
  __bf16* VT     = (__bf16*)alloc((size_t)D_ * M1_ * 2);  // 100.7 MB
  float*  logits = (float*)alloc((size_t)H_ * LL2_ * 4);  // 2.36 MB
  __bf16* attn   = (__bf16*)alloc((size_t)H_ * LL2_ * 2); // 1.18 MB
  __bf16* WvT    = (__bf16*)alloc((size_t)512 * 512 * 2);
  __bf16* WoT    = (__bf16*)alloc((size_t)512 * 512 * 2);
  __bf16* out2   = msa;  // msa dead after gemm_vt_kernel

  ln_wtrans_kernel<<<NLN_BLOCKS + 2048, 256, 0, stream>>>(
      x, g_msa, b_msa, msa, Wv, Wo, WvT, WoT);
  gemm_vt_kernel<<<dim3(2, M1_ / 256), 512, 0, stream>>>(WvT, msa, VT);
  pair_logits_kernel<<<NPAIR_BLOCKS, 256, 0, stream>>>(pair, mask, g_pair, b_pair, Wp, logits);
  softmax_kernel<<<(H_ * L_) / 4, 256, 0, stream>>>(logits, attn);
  attnv_kernel<<<dim3(3, RR_ * H_), 256, 0, stream>>>(attn, VT, out2);
  gemm_out_kernel<<<dim3(2, M1_ / 256), 512, 0, stream>>>(out2, WoT, x, out);
}